// Round 2
// baseline (272.926 us; speedup 1.0000x reference)
//
#include <hip/hip_runtime.h>
#include <hip/hip_bf16.h>

// BFConv2d on MI355X: BFP(8,16)-quantize x and w to bf16 (exact: q in
// [-127,127] * 2^(e-7) has <=8 significant bits), then implicit-GEMM 3x3
// conv with mfma_f32_16x16x32_bf16, fp32 accumulation.
// x (64,128,56,56) f32 NCHW; w (128,128,3,3) f32 OIHW; out (64,128,56,56) f32.
//
// conv structure (r2): weights are NOT staged in LDS -- wq is re-laid-out as
// [cblk][rs][k][c32] so each A-frag load is a coalesced 1KB wave read from
// L2-resident global (294KB total). Only Xs lives in LDS (double-buffered,
// 2x27.8KB); ONE barrier per cblk (5 total vs 72 in r1 design).

using short8 = __attribute__((ext_vector_type(8))) short;
using f32x4  = __attribute__((ext_vector_type(4))) float;
using int4v  = __attribute__((ext_vector_type(4))) int;

#define XS_STRIDE_S 40                    // shorts per Xs row: 32 payload + 8 pad (80B, 2-way banks = free)
#define XS_ENT      348                   // 6 rows x 58 cols
#define XS_BUF_S    (XS_ENT * XS_STRIDE_S)  // 13920 shorts = 27,840B per buffer

__device__ __forceinline__ unsigned short f2bf(float f) {
    union { float f; unsigned u; } v; v.f = f;
    return (unsigned short)(v.u >> 16);   // quantized values exact in bf16
}

__device__ __forceinline__ void quant16(const float* v, float* o) {
    float m = 0.f;
    #pragma unroll
    for (int i = 0; i < 16; ++i) m = fmaxf(m, fabsf(v[i]));
    if (m > 0.f) {
        float e     = floorf(log2f(m));   // matches jnp.floor(jnp.log2(m))
        float scale = exp2f(e - 7.0f);
        float inv   = exp2f(7.0f - e);
        #pragma unroll
        for (int i = 0; i < 16; ++i) {
            float q = rintf(v[i] * inv);  // round half-to-even == jnp.round
            q = fminf(fmaxf(q, -127.f), 127.f);
            o[i] = q * scale;
        }
    } else {
        #pragma unroll
        for (int i = 0; i < 16; ++i) o[i] = 0.f;
    }
}

// x NCHW f32 -> xq NHWC bf16. Group = 16 consecutive pixels of one (n,c) plane
// (3136 px/plane = 196 exact groups, flat-order groups never straddle planes).
__global__ __launch_bounds__(256) void quant_x_kernel(const float* __restrict__ x,
                                                      unsigned short* __restrict__ xq) {
    const int bid = blockIdx.x;
    const int n  = bid / 98;
    const int pb = bid % 98;
    const int t  = threadIdx.x;
    const int c  = t & 127;
    const int g  = t >> 7;
    const int p0 = pb * 32 + g * 16;

    const float* src = x + ((size_t)(n * 128 + c) * 3136 + p0);   // 64B/thread contiguous
    float v[16];
    #pragma unroll
    for (int i = 0; i < 4; ++i) {
        float4 f = *reinterpret_cast<const float4*>(src + i * 4);
        v[i*4+0] = f.x; v[i*4+1] = f.y; v[i*4+2] = f.z; v[i*4+3] = f.w;
    }
    float o[16];
    quant16(v, o);
    unsigned short* dst = xq + ((size_t)(n * 3136 + p0) * 128 + c);
    #pragma unroll
    for (int j = 0; j < 16; ++j) dst[(size_t)j * 128] = f2bf(o[j]);  // 128B/line coalesced
}

// w OIHW f32 -> wq [cblk][rs][k][c32] bf16 (c32 = c&31, cblk = c>>5).
// Group = 16 consecutive (c,r,s) of one k (1152/16 = 72 exact groups per k).
__global__ __launch_bounds__(256) void quant_w_kernel(const float* __restrict__ w,
                                                      unsigned short* __restrict__ wq) {
    const int G = blockIdx.x * 256 + threadIdx.x;   // 0..9215
    const int k    = G / 72;
    const int base = (G % 72) * 16;                 // flat idx2 = c*9 + r*3 + s
    const float* src = w + (size_t)k * 1152 + base;
    float v[16];
    #pragma unroll
    for (int i = 0; i < 4; ++i) {
        float4 f = *reinterpret_cast<const float4*>(src + i * 4);
        v[i*4+0] = f.x; v[i*4+1] = f.y; v[i*4+2] = f.z; v[i*4+3] = f.w;
    }
    float o[16];
    quant16(v, o);
    #pragma unroll
    for (int j = 0; j < 16; ++j) {
        int idx2 = base + j;
        int c  = idx2 / 9;
        int rs = idx2 % 9;
        wq[(((size_t)(c >> 5) * 9 + rs) * 128 + k) * 32 + (c & 31)] = f2bf(o[j]);
    }
}

// Implicit-GEMM conv. Per WG: n fixed, 4 output rows (224 px = 4x56), all 128 k.
// Waves 2x2: wave tile = 112 px x 64 k = 7 M-frags x 4 N-frags (16x16x32 bf16).
// A-op = weights (rows = k) from GLOBAL, B-op = Xs pixels (cols) from LDS, K-dim = c.
__global__ __launch_bounds__(256, 2) void conv_kernel(const unsigned short* __restrict__ xq,
                                                      const unsigned short* __restrict__ wq,
                                                      float* __restrict__ out) {
    __shared__ __align__(16) unsigned short Xs[2 * XS_BUF_S];   // 55,680B -> 2 blocks/CU

    const int bid  = blockIdx.x;          // 896 = 64 n * 14 h-tiles
    const int n    = bid / 14;
    const int h0   = (bid % 14) * 4;
    const int t    = threadIdx.x;
    const int lane = t & 63;
    const int wave = t >> 6;
    const int mw   = wave >> 1;           // pixel half
    const int nw   = wave & 1;            // k half

    // ---- staging descriptors: 6 x 16B chunks per thread, fixed across cblk ----
    const unsigned short* sbase[6];
    int  soff[6];
    bool svalid[6], sact[6];
    #pragma unroll
    for (int it = 0; it < 6; ++it) {
        int i   = t + it * 256;
        bool act = i < 1392;              // 348 entries * 4 chunks
        int e   = i >> 2, cc = i & 3;
        int row = e / 58, pw = e % 58;
        int h   = h0 - 1 + row, w_ = pw - 1;
        bool inb = act && (unsigned)h < 56u && (unsigned)w_ < 56u;
        int gidx = inb ? (n * 3136 + h * 56 + w_) : 0;
        sbase[it]  = xq + (size_t)gidx * 128 + cc * 8;
        soff[it]   = e * XS_STRIDE_S + cc * 8;
        svalid[it] = inb;
        sact[it]   = act;
    }
    int4v sreg[6];

#define STAGE_LOAD(CB) do {                                                    \
    _Pragma("unroll")                                                          \
    for (int it = 0; it < 6; ++it)                                             \
        sreg[it] = svalid[it]                                                  \
            ? *reinterpret_cast<const int4v*>(sbase[it] + (CB) * 32)           \
            : int4v{0, 0, 0, 0};                                               \
} while (0)

#define STAGE_WRITE(BUFS) do {                                                 \
    _Pragma("unroll")                                                          \
    for (int it = 0; it < 6; ++it)                                             \
        if (sact[it])                                                          \
            *reinterpret_cast<int4v*>(Xs + (BUFS) + soff[it]) = sreg[it];      \
} while (0)

    // ---- per-lane fragment offsets ----
    int boff[7];                          // B-frag (pixels) LDS short-offsets
    #pragma unroll
    for (int fi = 0; fi < 7; ++fi) {
        int m  = mw * 112 + fi * 16 + (lane & 15);
        int dh = m / 56, w_ = m % 56;
        boff[fi] = (dh * 58 + w_) * XS_STRIDE_S + ((lane >> 4) * 8);
    }
    // A-frag: element ((cblk*9+rs)*128 + nw*64 + ni*16 + (lane&15))*32 + (lane>>4)*8
    const unsigned short* wk = wq + (size_t)(nw * 64 + (lane & 15)) * 32 + ((lane >> 4) * 8);

    f32x4 acc[7][4];
    #pragma unroll
    for (int fi = 0; fi < 7; ++fi)
        #pragma unroll
        for (int ni = 0; ni < 4; ++ni)
            acc[fi][ni] = f32x4{0.f, 0.f, 0.f, 0.f};

#define RS_STEP(RS) do {                                                       \
    const int rsS = (((RS) / 3) * 58 + ((RS) % 3)) * XS_STRIDE_S;              \
    short8 a[4], b[7];                                                         \
    _Pragma("unroll")                                                          \
    for (int ni = 0; ni < 4; ++ni)                                             \
        a[ni] = *reinterpret_cast<const short8*>(wcb + (RS) * 4096 + ni * 512);\
    _Pragma("unroll")                                                          \
    for (int fi = 0; fi < 7; ++fi)                                             \
        b[fi] = *reinterpret_cast<const short8*>(Xs + bufS + boff[fi] + rsS);  \
    _Pragma("unroll")                                                          \
    for (int fi = 0; fi < 7; ++fi)                                             \
        _Pragma("unroll")                                                      \
        for (int ni = 0; ni < 4; ++ni)                                         \
            acc[fi][ni] = __builtin_amdgcn_mfma_f32_16x16x32_bf16(             \
                a[ni], b[fi], acc[fi][ni], 0, 0, 0);                           \
} while (0)

    // ---- prologue: stage cblk 0 into buf 0 ----
    STAGE_LOAD(0);
    STAGE_WRITE(0);
    __syncthreads();

    for (int cblk = 0; cblk < 4; ++cblk) {
        const int bufS = (cblk & 1) * XS_BUF_S;
        const unsigned short* wcb = wk + (size_t)cblk * 9 * 4096;
        RS_STEP(0);
        if (cblk < 3) STAGE_LOAD(cblk + 1);       // issue after rs0's loads (vmcnt order)
        RS_STEP(1); RS_STEP(2); RS_STEP(3); RS_STEP(4);
        RS_STEP(5); RS_STEP(6); RS_STEP(7); RS_STEP(8);
        if (cblk < 3) STAGE_WRITE(((cblk + 1) & 1) * XS_BUF_S);
        __syncthreads();                          // buf ready for next iter; reads of bufS done
    }

    // ---- epilogue: D col = pixel = lane&15, row = k = (lane>>4)*4 + reg (m89) ----
    const int pix0  = h0 * 56 + mw * 112 + (lane & 15);
    const int krow0 = n * 128 + nw * 64 + ((lane >> 4) * 4);
    #pragma unroll
    for (int fi = 0; fi < 7; ++fi)
        #pragma unroll
        for (int ni = 0; ni < 4; ++ni)
            #pragma unroll
            for (int j = 0; j < 4; ++j)
                out[(size_t)(krow0 + ni * 16 + j) * 3136 + pix0 + fi * 16] = acc[fi][ni][j];
#undef RS_STEP
#undef STAGE_LOAD
#undef STAGE_WRITE
}

extern "C" void kernel_launch(void* const* d_in, const int* in_sizes, int n_in,
                              void* d_out, int out_size, void* d_ws, size_t ws_size,
                              hipStream_t stream) {
    const float* x = (const float*)d_in[0];   // 25,690,112 f32
    const float* w = (const float*)d_in[1];   //    147,456 f32
    float* out = (float*)d_out;               // 25,690,112 f32

    // Workspace: xq (NHWC bf16, 51.4MB) + wq ([cblk][rs][k][c32] bf16, 0.3MB)
    unsigned short* xq = (unsigned short*)d_ws;
    unsigned short* wq = xq + (size_t)25690112;

    quant_x_kernel<<<64 * 98, 256, 0, stream>>>(x, xq);
    quant_w_kernel<<<36,      256, 0, stream>>>(w, wq);
    conv_kernel  <<<896,      256, 0, stream>>>(xq, wq, out);
}

// Round 3
// 257.490 us; speedup vs baseline: 1.0599x; 1.0599x over previous
//
#include <hip/hip_runtime.h>
#include <hip/hip_bf16.h>

// BFConv2d on MI355X: BFP(8,16)-quantize x and w to bf16 (exact: q in
// [-127,127] * 2^(e-7) has <=8 significant bits), then implicit-GEMM 3x3
// conv with mfma_f32_16x16x32_bf16, fp32 accumulation.
// x (64,128,56,56) f32 NCHW; w (128,128,3,3) f32 OIHW; out (64,128,56,56) f32.
//
// r3: (1) quant_x via LDS transpose -> fully coalesced NCHW reads (was
// plane-strided per lane = ~2x overfetch); quant_w folded into same launch.
// (2) conv: A-frag (weights) software-pipelined one rs-step ahead -> L2
// latency hidden under MFMAs. (3) XCD-aware block swizzle on conv.

using short8 = __attribute__((ext_vector_type(8))) short;
using f32x4  = __attribute__((ext_vector_type(4))) float;
using int4v  = __attribute__((ext_vector_type(4))) int;

#define XS_STRIDE_S 40                      // shorts per Xs row (80B: 16B-aligned, ~2-4 way banks)
#define XS_ENT      348                     // 6 rows x 58 cols
#define XS_BUF_S    (XS_ENT * XS_STRIDE_S)  // 13920 shorts = 27,840B per buffer

__device__ __forceinline__ unsigned short f2bf(float f) {
    union { float f; unsigned u; } v; v.f = f;
    return (unsigned short)(v.u >> 16);     // quantized values exact in bf16
}

__device__ __forceinline__ void quant16(const float* v, float* o) {
    float m = 0.f;
    #pragma unroll
    for (int i = 0; i < 16; ++i) m = fmaxf(m, fabsf(v[i]));
    if (m > 0.f) {
        float e     = floorf(log2f(m));     // matches jnp.floor(jnp.log2(m))
        float scale = exp2f(e - 7.0f);
        float inv   = exp2f(7.0f - e);
        #pragma unroll
        for (int i = 0; i < 16; ++i) {
            float q = rintf(v[i] * inv);    // round half-to-even == jnp.round
            q = fminf(fmaxf(q, -127.f), 127.f);
            o[i] = q * scale;
        }
    } else {
        #pragma unroll
        for (int i = 0; i < 16; ++i) o[i] = 0.f;
    }
}

// Fused quantization. Blocks 0..3135: x NCHW f32 -> xq NHWC bf16 via LDS
// transpose (tile = 128c x 64px). Blocks 3136..3171: w OIHW f32 ->
// wq [cblk][rs][k][c32] bf16. Groups of 16 never straddle tiles (64%16==0,
// plane = 3136 px = 196 exact groups; per-k 1152 = 72 exact groups).
__global__ __launch_bounds__(256) void quant_kernel(const float* __restrict__ x,
                                                    const float* __restrict__ w,
                                                    unsigned short* __restrict__ xq,
                                                    unsigned short* __restrict__ wq) {
    __shared__ float T[128 * 68];           // 34,816B; row stride 68 (272B, 16B-aligned)
    const int bid = blockIdx.x;
    const int t   = threadIdx.x;

    if (bid < 3136) {
        const int n  = bid / 49;
        const int p0 = (bid % 49) * 64;
        const float* src = x + (size_t)n * 128 * 3136 + p0;

        // Phase 1: coalesced NCHW read. Wave: lanes 0-15 = 256B of row c,
        // lanes 16-31 next row, ... -> 4x256B full-line segments per inst.
        #pragma unroll
        for (int i = 0; i < 8; ++i) {
            const int c  = (t >> 4) + i * 16;
            const int ch = t & 15;
            *reinterpret_cast<float4*>(&T[c * 68 + ch * 4]) =
                *reinterpret_cast<const float4*>(src + (size_t)c * 3136 + ch * 4);
        }
        __syncthreads();

        // Phase 2: thread = one (c, 16-px group); write NHWC (wave = 128B
        // contiguous per j across c-lanes).
        const int c = t & 127;
        #pragma unroll
        for (int i = 0; i < 2; ++i) {
            const int grp = (t >> 7) + 2 * i;
            float v[16];
            #pragma unroll
            for (int j2 = 0; j2 < 4; ++j2) {
                float4 f = *reinterpret_cast<const float4*>(&T[c * 68 + grp * 16 + j2 * 4]);
                v[j2*4+0] = f.x; v[j2*4+1] = f.y; v[j2*4+2] = f.z; v[j2*4+3] = f.w;
            }
            float o[16];
            quant16(v, o);
            unsigned short* dst = xq + ((size_t)(n * 3136 + p0 + grp * 16)) * 128 + c;
            #pragma unroll
            for (int j = 0; j < 16; ++j) dst[(size_t)j * 128] = f2bf(o[j]);
        }
    } else {
        const int G    = (bid - 3136) * 256 + t;   // 0..9215
        const int k    = G / 72;
        const int base = (G % 72) * 16;            // flat idx2 = c*9 + r*3 + s
        const float* src = w + (size_t)k * 1152 + base;
        float v[16];
        #pragma unroll
        for (int i = 0; i < 4; ++i) {
            float4 f = *reinterpret_cast<const float4*>(src + i * 4);
            v[i*4+0] = f.x; v[i*4+1] = f.y; v[i*4+2] = f.z; v[i*4+3] = f.w;
        }
        float o[16];
        quant16(v, o);
        #pragma unroll
        for (int j = 0; j < 16; ++j) {
            int idx2 = base + j;
            int c  = idx2 / 9;
            int rs = idx2 % 9;
            wq[(((size_t)(c >> 5) * 9 + rs) * 128 + k) * 32 + (c & 31)] = f2bf(o[j]);
        }
    }
}

// Implicit-GEMM conv. Per WG: n fixed, 4 output rows (224 px = 4x56), all 128 k.
// Waves 2x2: wave tile = 112 px x 64 k = 7 M-frags x 4 N-frags (16x16x32 bf16).
// A-op = weights (rows = k) from L2-resident GLOBAL (software-pipelined one
// step ahead), B-op = Xs pixels (cols) from LDS (double-buffered), K-dim = c.
__global__ __launch_bounds__(256, 2) void conv_kernel(const unsigned short* __restrict__ xq,
                                                      const unsigned short* __restrict__ wq,
                                                      float* __restrict__ out) {
    __shared__ __align__(16) unsigned short Xs[2 * XS_BUF_S];   // 55,680B -> 2 blocks/CU

    const int b0   = blockIdx.x;          // 896 = 64 n * 14 h-tiles
    const int bid  = (b0 & 7) * 112 + (b0 >> 3);   // XCD swizzle (bijective: 896%8==0)
    const int n    = bid / 14;
    const int h0   = (bid % 14) * 4;
    const int t    = threadIdx.x;
    const int lane = t & 63;
    const int wave = t >> 6;
    const int mw   = wave >> 1;           // pixel half
    const int nw   = wave & 1;            // k half

    // ---- staging descriptors: 6 x 16B chunks per thread, fixed across cblk ----
    const unsigned short* sbase[6];
    int  soff[6];
    bool svalid[6], sact[6];
    #pragma unroll
    for (int it = 0; it < 6; ++it) {
        int i   = t + it * 256;
        bool act = i < 1392;              // 348 entries * 4 chunks
        int e   = i >> 2, cc = i & 3;
        int row = e / 58, pw = e % 58;
        int h   = h0 - 1 + row, w_ = pw - 1;
        bool inb = act && (unsigned)h < 56u && (unsigned)w_ < 56u;
        int gidx = inb ? (n * 3136 + h * 56 + w_) : 0;
        sbase[it]  = xq + (size_t)gidx * 128 + cc * 8;
        soff[it]   = e * XS_STRIDE_S + cc * 8;
        svalid[it] = inb;
        sact[it]   = act;
    }
    int4v sreg[6];

#define STAGE_LOAD(CB) do {                                                    \
    _Pragma("unroll")                                                          \
    for (int it = 0; it < 6; ++it)                                             \
        sreg[it] = svalid[it]                                                  \
            ? *reinterpret_cast<const int4v*>(sbase[it] + (CB) * 32)           \
            : int4v{0, 0, 0, 0};                                               \
} while (0)

#define STAGE_WRITE(BUFS) do {                                                 \
    _Pragma("unroll")                                                          \
    for (int it = 0; it < 6; ++it)                                             \
        if (sact[it])                                                          \
            *reinterpret_cast<int4v*>(Xs + (BUFS) + soff[it]) = sreg[it];      \
} while (0)

    // ---- per-lane fragment offsets ----
    int boff[7];                          // B-frag (pixels) LDS short-offsets
    #pragma unroll
    for (int fi = 0; fi < 7; ++fi) {
        int m  = mw * 112 + fi * 16 + (lane & 15);
        int dh = m / 56, w_ = m % 56;
        boff[fi] = (dh * 58 + w_) * XS_STRIDE_S + ((lane >> 4) * 8);
    }
    // A-frag element: (step*128 + nw*64 + ni*16 + (lane&15))*32 + (lane>>4)*8
    const unsigned short* wk = wq + (size_t)(nw * 64 + (lane & 15)) * 32 + ((lane >> 4) * 8);

#define LOADA(DST, STEP) do {                                                  \
    _Pragma("unroll")                                                          \
    for (int ni = 0; ni < 4; ++ni)                                             \
        DST[ni] = *reinterpret_cast<const short8*>(                            \
            wk + (size_t)(STEP) * 4096 + ni * 512);                            \
} while (0)

    f32x4 acc[7][4];
    #pragma unroll
    for (int fi = 0; fi < 7; ++fi)
        #pragma unroll
        for (int ni = 0; ni < 4; ++ni)
            acc[fi][ni] = f32x4{0.f, 0.f, 0.f, 0.f};

    short8 a_cur[4], a_nxt[4];

    // ---- prologue: stage cblk 0 into buf 0; preload step-0 weights ----
    STAGE_LOAD(0);
    LOADA(a_cur, 0);
    STAGE_WRITE(0);
    __syncthreads();

    #pragma unroll
    for (int step = 0; step < 36; ++step) {
        const int cblk = step / 9;
        const int rs   = step % 9;
        const int bufS = (cblk & 1) * XS_BUF_S;

        if (step < 35) LOADA(a_nxt, step + 1);          // prefetch next weights
        if (rs == 0 && cblk < 3) STAGE_LOAD(cblk + 1);  // issue next-cblk x loads

        const int rsS = ((rs / 3) * 58 + (rs % 3)) * XS_STRIDE_S;
        short8 b[7];
        #pragma unroll
        for (int fi = 0; fi < 7; ++fi)
            b[fi] = *reinterpret_cast<const short8*>(Xs + bufS + boff[fi] + rsS);

        #pragma unroll
        for (int fi = 0; fi < 7; ++fi)
            #pragma unroll
            for (int ni = 0; ni < 4; ++ni)
                acc[fi][ni] = __builtin_amdgcn_mfma_f32_16x16x32_bf16(
                    a_cur[ni], b[fi], acc[fi][ni], 0, 0, 0);

        if (rs == 8) {
            if (cblk < 3) STAGE_WRITE(((cblk + 1) & 1) * XS_BUF_S);
            __syncthreads();              // next buf ready; current-buf reads done
        }
        #pragma unroll
        for (int ni = 0; ni < 4; ++ni) a_cur[ni] = a_nxt[ni];
    }

    // ---- epilogue: D col = pixel = lane&15, row = k = (lane>>4)*4 + reg (m89) ----
    const int pix0  = h0 * 56 + mw * 112 + (lane & 15);
    const int krow0 = n * 128 + nw * 64 + ((lane >> 4) * 4);
    #pragma unroll
    for (int fi = 0; fi < 7; ++fi)
        #pragma unroll
        for (int ni = 0; ni < 4; ++ni)
            #pragma unroll
            for (int j = 0; j < 4; ++j)
                out[(size_t)(krow0 + ni * 16 + j) * 3136 + pix0 + fi * 16] = acc[fi][ni][j];
#undef LOADA
#undef STAGE_LOAD
#undef STAGE_WRITE
}

extern "C" void kernel_launch(void* const* d_in, const int* in_sizes, int n_in,
                              void* d_out, int out_size, void* d_ws, size_t ws_size,
                              hipStream_t stream) {
    const float* x = (const float*)d_in[0];   // 25,690,112 f32
    const float* w = (const float*)d_in[1];   //    147,456 f32
    float* out = (float*)d_out;               // 25,690,112 f32

    // Workspace: xq (NHWC bf16, 51.4MB) + wq ([cblk][rs][k][c32] bf16, 0.3MB)
    unsigned short* xq = (unsigned short*)d_ws;
    unsigned short* wq = xq + (size_t)25690112;

    quant_kernel<<<3136 + 36, 256, 0, stream>>>(x, w, xq, wq);
    conv_kernel <<<896,       256, 0, stream>>>(xq, wq, out);
}